// Round 1
// baseline (1589.637 us; speedup 1.0000x reference)
//
#include <hip/hip_runtime.h>
#include <hip/hip_bf16.h>

#define THREADS 256

// ---------------------------------------------------------------------------
// Dual GEMM: outl = in @ Wl, outr = in @ Wr.   in: [nrows, K], W: [K, 64].
// One wave per row (wave-uniform row => scalar loads of x), W in LDS.
// ---------------------------------------------------------------------------
template<int K>
__global__ __launch_bounds__(THREADS) void gemm_dual(
    const float* __restrict__ in, const float* __restrict__ Wl,
    const float* __restrict__ Wr, float* __restrict__ outl,
    float* __restrict__ outr, int nrows)
{
    __shared__ float sWl[K * 64];
    __shared__ float sWr[K * 64];
    for (int i = threadIdx.x; i < K * 64; i += THREADS) {
        sWl[i] = Wl[i];
        sWr[i] = Wr[i];
    }
    __syncthreads();

    const int lane = threadIdx.x & 63;
    const int wid  = threadIdx.x >> 6;
    const int ngroups = (nrows + 3) >> 2;

    for (int grp = blockIdx.x; grp < ngroups; grp += gridDim.x) {
        int row = grp * 4 + wid;
        if (row < nrows) {
            row = __builtin_amdgcn_readfirstlane(row);   // wave-uniform
            const float4* xr = reinterpret_cast<const float4*>(in + (size_t)row * K);
            float accl = 0.f, accr = 0.f;
            #pragma unroll
            for (int k4 = 0; k4 < K / 4; ++k4) {
                const float4 xv = xr[k4];
                const int kb = k4 * 4;
                accl = fmaf(xv.x, sWl[(kb + 0) * 64 + lane], accl);
                accr = fmaf(xv.x, sWr[(kb + 0) * 64 + lane], accr);
                accl = fmaf(xv.y, sWl[(kb + 1) * 64 + lane], accl);
                accr = fmaf(xv.y, sWr[(kb + 1) * 64 + lane], accr);
                accl = fmaf(xv.z, sWl[(kb + 2) * 64 + lane], accl);
                accr = fmaf(xv.z, sWr[(kb + 2) * 64 + lane], accr);
                accl = fmaf(xv.w, sWl[(kb + 3) * 64 + lane], accl);
                accr = fmaf(xv.w, sWr[(kb + 3) * 64 + lane], accr);
            }
            outl[(size_t)row * 64 + lane] = accl;
            outr[(size_t)row * 64 + lane] = accr;
        }
    }
}

// ---------------------------------------------------------------------------
// Scatter-add y[src[e]] (64 floats) into agg[dst[e]]; 16 lanes per edge,
// float4 per lane. Optionally counts in-degree into cnt.
// ---------------------------------------------------------------------------
__global__ __launch_bounds__(THREADS) void scatter_kernel(
    const float* __restrict__ y, const int* __restrict__ src,
    const int* __restrict__ dst, float* __restrict__ agg,
    float* __restrict__ cnt, int nedges, int do_cnt)
{
    const int gid = blockIdx.x * THREADS + threadIdx.x;
    const int e = gid >> 4;
    const int g = gid & 15;
    if (e >= nedges) return;
    const int s = src[e];
    const int d = dst[e];
    const float4 v = *reinterpret_cast<const float4*>(y + (size_t)s * 64 + g * 4);
    float* a = agg + (size_t)d * 64 + g * 4;
    unsafeAtomicAdd(a + 0, v.x);
    unsafeAtomicAdd(a + 1, v.y);
    unsafeAtomicAdd(a + 2, v.z);
    unsafeAtomicAdd(a + 3, v.w);
    if (do_cnt && g == 0) unsafeAtomicAdd(cnt + d, 1.0f);
}

// ---------------------------------------------------------------------------
// io = [relu]( agg / max(cnt,1) + bias + io )   (io holds x @ Wr on entry)
// One thread per 4 channels.
// ---------------------------------------------------------------------------
__global__ __launch_bounds__(THREADS) void combine_kernel(
    float* __restrict__ io, const float* __restrict__ agg,
    const float* __restrict__ cnt, const float* __restrict__ bias,
    int nrows, int relu)
{
    const int gid = blockIdx.x * THREADS + threadIdx.x;
    const int total = nrows * 16;
    if (gid >= total) return;
    const int row = gid >> 4;
    const int g = gid & 15;
    const float inv = 1.0f / fmaxf(cnt[row], 1.0f);
    const float4 a = *reinterpret_cast<const float4*>(agg + (size_t)gid * 4);
    const float4 b = *reinterpret_cast<const float4*>(bias + g * 4);
    float4 v = *reinterpret_cast<float4*>(io + (size_t)gid * 4);
    v.x = fmaf(a.x, inv, v.x + b.x);
    v.y = fmaf(a.y, inv, v.y + b.y);
    v.z = fmaf(a.z, inv, v.z + b.z);
    v.w = fmaf(a.w, inv, v.w + b.w);
    if (relu) {
        v.x = fmaxf(v.x, 0.f); v.y = fmaxf(v.y, 0.f);
        v.z = fmaxf(v.z, 0.f); v.w = fmaxf(v.w, 0.f);
    }
    *reinterpret_cast<float4*>(io + (size_t)gid * 4) = v;
}

// ---------------------------------------------------------------------------
// out[e] = dot(z[src[e]], z[dst[e]])  over 64 ch; 16 lanes/edge + shfl reduce.
// ---------------------------------------------------------------------------
__global__ __launch_bounds__(THREADS) void score_kernel(
    const float* __restrict__ z, const int* __restrict__ src,
    const int* __restrict__ dst, float* __restrict__ out, int nedges)
{
    const int gid = blockIdx.x * THREADS + threadIdx.x;
    const int e = gid >> 4;
    const int g = gid & 15;
    if (e >= nedges) return;
    const int s = src[e];
    const int d = dst[e];
    const float4 a = *reinterpret_cast<const float4*>(z + (size_t)s * 64 + g * 4);
    const float4 b = *reinterpret_cast<const float4*>(z + (size_t)d * 64 + g * 4);
    float p = a.x * b.x + a.y * b.y + a.z * b.z + a.w * b.w;
    p += __shfl_down(p, 8, 16);
    p += __shfl_down(p, 4, 16);
    p += __shfl_down(p, 2, 16);
    p += __shfl_down(p, 1, 16);
    if (g == 0) out[e] = p;
}

extern "C" void kernel_launch(void* const* d_in, const int* in_sizes, int n_in,
                              void* d_out, int out_size, void* d_ws, size_t ws_size,
                              hipStream_t stream)
{
    const float* x   = (const float*)d_in[0];   // [N, 128]
    const int*   ei  = (const int*)  d_in[1];   // [2, E]
    const float* W1l = (const float*)d_in[2];   // [128, 64]
    const float* b1  = (const float*)d_in[3];   // [64]
    const float* W1r = (const float*)d_in[4];   // [128, 64]
    const float* W2l = (const float*)d_in[5];   // [64, 64]
    const float* b2  = (const float*)d_in[6];   // [64]
    const float* W2r = (const float*)d_in[7];   // [64, 64]
    float* out = (float*)d_out;

    const int N = in_sizes[0] / 128;            // 50000
    const int E = in_sizes[1] / 2;              // 800000
    const int* src = ei;
    const int* dst = ei + E;

    const size_t N64 = (size_t)N * 64;
    float* tmp = (float*)d_ws;                  // [N,64]  y = in @ Wl
    float* agg = tmp + N64;                     // [N,64]  scatter accumulator
    float* h   = agg + N64;                     // [N,64]  layer-1 output
    float* z   = h + N64;                       // [N,64]  layer-2 output
    float* cnt = z + N64;                       // [N]     in-degree

    const int gemm_blocks = 2048;
    const int scat_blocks = (E * 16 + THREADS - 1) / THREADS;
    const int comb_blocks = (N * 16 + THREADS - 1) / THREADS;

    // ---- layer 1 ----
    hipMemsetAsync(agg, 0, N64 * sizeof(float), stream);
    hipMemsetAsync(cnt, 0, (size_t)N * sizeof(float), stream);
    gemm_dual<128><<<gemm_blocks, THREADS, 0, stream>>>(x, W1l, W1r, tmp, h, N);
    scatter_kernel<<<scat_blocks, THREADS, 0, stream>>>(tmp, src, dst, agg, cnt, E, 1);
    combine_kernel<<<comb_blocks, THREADS, 0, stream>>>(h, agg, cnt, b1, N, 1);

    // ---- layer 2 ----
    hipMemsetAsync(agg, 0, N64 * sizeof(float), stream);
    gemm_dual<64><<<gemm_blocks, THREADS, 0, stream>>>(h, W2l, W2r, tmp, z, N);
    scatter_kernel<<<scat_blocks, THREADS, 0, stream>>>(tmp, src, dst, agg, cnt, E, 0);
    combine_kernel<<<comb_blocks, THREADS, 0, stream>>>(z, agg, cnt, b2, N, 0);

    // ---- decode ----
    score_kernel<<<scat_blocks, THREADS, 0, stream>>>(z, src, dst, out, E);
}

// Round 2
// 332.599 us; speedup vs baseline: 4.7794x; 4.7794x over previous
//
#include <hip/hip_runtime.h>
#include <hip/hip_bf16.h>

#define THREADS 256

// ---------------------------------------------------------------------------
// Dual GEMM: outl = in @ Wl, outr = in @ Wr.   in: [nrows, K], W: [K, 64].
// One wave per row (wave-uniform row => scalar loads of x), W in LDS.
// ---------------------------------------------------------------------------
template<int K>
__global__ __launch_bounds__(THREADS) void gemm_dual(
    const float* __restrict__ in, const float* __restrict__ Wl,
    const float* __restrict__ Wr, float* __restrict__ outl,
    float* __restrict__ outr, int nrows)
{
    __shared__ float sWl[K * 64];
    __shared__ float sWr[K * 64];
    for (int i = threadIdx.x; i < K * 64; i += THREADS) {
        sWl[i] = Wl[i];
        sWr[i] = Wr[i];
    }
    __syncthreads();

    const int lane = threadIdx.x & 63;
    const int wid  = threadIdx.x >> 6;
    const int ngroups = (nrows + 3) >> 2;

    for (int grp = blockIdx.x; grp < ngroups; grp += gridDim.x) {
        int row = grp * 4 + wid;
        if (row < nrows) {
            row = __builtin_amdgcn_readfirstlane(row);   // wave-uniform
            const float4* xr = reinterpret_cast<const float4*>(in + (size_t)row * K);
            float accl = 0.f, accr = 0.f;
            #pragma unroll
            for (int k4 = 0; k4 < K / 4; ++k4) {
                const float4 xv = xr[k4];
                const int kb = k4 * 4;
                accl = fmaf(xv.x, sWl[(kb + 0) * 64 + lane], accl);
                accr = fmaf(xv.x, sWr[(kb + 0) * 64 + lane], accr);
                accl = fmaf(xv.y, sWl[(kb + 1) * 64 + lane], accl);
                accr = fmaf(xv.y, sWr[(kb + 1) * 64 + lane], accr);
                accl = fmaf(xv.z, sWl[(kb + 2) * 64 + lane], accl);
                accr = fmaf(xv.z, sWr[(kb + 2) * 64 + lane], accr);
                accl = fmaf(xv.w, sWl[(kb + 3) * 64 + lane], accl);
                accr = fmaf(xv.w, sWr[(kb + 3) * 64 + lane], accr);
            }
            outl[(size_t)row * 64 + lane] = accl;
            outr[(size_t)row * 64 + lane] = accr;
        }
    }
}

// ---------------------------------------------------------------------------
// CSR build: histogram of dst, exclusive scan, placement.
// ---------------------------------------------------------------------------
__global__ __launch_bounds__(THREADS) void hist_kernel(
    const int* __restrict__ dst, int* __restrict__ deg, int nedges)
{
    const int e = blockIdx.x * THREADS + threadIdx.x;
    if (e < nedges) atomicAdd(&deg[dst[e]], 1);
}

__global__ __launch_bounds__(THREADS) void scan_reduce(
    const int* __restrict__ deg, int* __restrict__ bsum, int n)
{
    __shared__ int s[THREADS];
    const int i = blockIdx.x * THREADS + threadIdx.x;
    s[threadIdx.x] = (i < n) ? deg[i] : 0;
    __syncthreads();
    for (int off = THREADS / 2; off > 0; off >>= 1) {
        if (threadIdx.x < off) s[threadIdx.x] += s[threadIdx.x + off];
        __syncthreads();
    }
    if (threadIdx.x == 0) bsum[blockIdx.x] = s[0];
}

// single block; nb <= THREADS
__global__ __launch_bounds__(THREADS) void scan_top(int* __restrict__ bsum, int nb)
{
    __shared__ int s[THREADS];
    const int t = threadIdx.x;
    const int v = (t < nb) ? bsum[t] : 0;
    s[t] = v;
    __syncthreads();
    for (int off = 1; off < THREADS; off <<= 1) {
        const int a = (t >= off) ? s[t - off] : 0;
        __syncthreads();
        s[t] += a;
        __syncthreads();
    }
    if (t < nb) bsum[t] = s[t] - v;   // exclusive
}

__global__ __launch_bounds__(THREADS) void scan_apply(
    const int* __restrict__ deg, const int* __restrict__ bsum,
    int* __restrict__ offs, int* __restrict__ cursor, int n)
{
    __shared__ int s[THREADS];
    const int t = threadIdx.x;
    const int i = blockIdx.x * THREADS + t;
    const int v = (i < n) ? deg[i] : 0;
    s[t] = v;
    __syncthreads();
    for (int off = 1; off < THREADS; off <<= 1) {
        const int a = (t >= off) ? s[t - off] : 0;
        __syncthreads();
        s[t] += a;
        __syncthreads();
    }
    if (i < n) {
        const int ex = bsum[blockIdx.x] + s[t] - v;
        offs[i] = ex;
        cursor[i] = ex;
    }
}

__global__ __launch_bounds__(THREADS) void place_kernel(
    const int* __restrict__ src, const int* __restrict__ dst,
    int* __restrict__ cursor, int* __restrict__ csr, int nedges)
{
    const int e = blockIdx.x * THREADS + threadIdx.x;
    if (e < nedges) {
        const int pos = atomicAdd(&cursor[dst[e]], 1);
        csr[pos] = src[e];
    }
}

// ---------------------------------------------------------------------------
// Fused mean-aggregate + combine:
//   out[node,lane] = [relu]( (sum_{s in csr[node]} y[s,lane]) / max(deg,1)
//                            + bias[lane] + right[node,lane] )
// One wave per node, lane = channel. Edge rows are coalesced 256B gathers.
// ---------------------------------------------------------------------------
__global__ __launch_bounds__(THREADS) void aggregate_fused(
    const float* __restrict__ y, const int* __restrict__ csr,
    const int* __restrict__ offs, const int* __restrict__ deg,
    const float* __restrict__ right, const float* __restrict__ bias,
    float* __restrict__ out, int n, int relu)
{
    int node = blockIdx.x * (THREADS / 64) + (threadIdx.x >> 6);
    if (node >= n) return;
    node = __builtin_amdgcn_readfirstlane(node);   // wave-uniform
    const int lane = threadIdx.x & 63;
    const int start = __builtin_amdgcn_readfirstlane(offs[node]);
    const int d     = __builtin_amdgcn_readfirstlane(deg[node]);

    float acc = 0.f;
    int i = 0;
    for (; i + 4 <= d; i += 4) {
        const int s0 = __builtin_amdgcn_readfirstlane(csr[start + i + 0]);
        const int s1 = __builtin_amdgcn_readfirstlane(csr[start + i + 1]);
        const int s2 = __builtin_amdgcn_readfirstlane(csr[start + i + 2]);
        const int s3 = __builtin_amdgcn_readfirstlane(csr[start + i + 3]);
        const float a0 = y[(size_t)s0 * 64 + lane];
        const float a1 = y[(size_t)s1 * 64 + lane];
        const float a2 = y[(size_t)s2 * 64 + lane];
        const float a3 = y[(size_t)s3 * 64 + lane];
        acc += a0 + a1 + a2 + a3;
    }
    for (; i < d; ++i) {
        const int s = __builtin_amdgcn_readfirstlane(csr[start + i]);
        acc += y[(size_t)s * 64 + lane];
    }

    const float inv = 1.0f / (float)(d > 0 ? d : 1);
    float v = fmaf(acc, inv, bias[lane] + right[(size_t)node * 64 + lane]);
    if (relu) v = fmaxf(v, 0.f);
    out[(size_t)node * 64 + lane] = v;
}

// ---------------------------------------------------------------------------
// out[e] = dot(z[src[e]], z[dst[e]])  over 64 ch; 16 lanes/edge + shfl reduce.
// ---------------------------------------------------------------------------
__global__ __launch_bounds__(THREADS) void score_kernel(
    const float* __restrict__ z, const int* __restrict__ src,
    const int* __restrict__ dst, float* __restrict__ out, int nedges)
{
    const int gid = blockIdx.x * THREADS + threadIdx.x;
    const int e = gid >> 4;
    const int g = gid & 15;
    if (e >= nedges) return;
    const int s = src[e];
    const int d = dst[e];
    const float4 a = *reinterpret_cast<const float4*>(z + (size_t)s * 64 + g * 4);
    const float4 b = *reinterpret_cast<const float4*>(z + (size_t)d * 64 + g * 4);
    float p = a.x * b.x + a.y * b.y + a.z * b.z + a.w * b.w;
    p += __shfl_down(p, 8, 16);
    p += __shfl_down(p, 4, 16);
    p += __shfl_down(p, 2, 16);
    p += __shfl_down(p, 1, 16);
    if (g == 0) out[e] = p;
}

extern "C" void kernel_launch(void* const* d_in, const int* in_sizes, int n_in,
                              void* d_out, int out_size, void* d_ws, size_t ws_size,
                              hipStream_t stream)
{
    const float* x   = (const float*)d_in[0];   // [N, 128]
    const int*   ei  = (const int*)  d_in[1];   // [2, E]
    const float* W1l = (const float*)d_in[2];   // [128, 64]
    const float* b1  = (const float*)d_in[3];   // [64]
    const float* W1r = (const float*)d_in[4];   // [128, 64]
    const float* W2l = (const float*)d_in[5];   // [64, 64]
    const float* b2  = (const float*)d_in[6];   // [64]
    const float* W2r = (const float*)d_in[7];   // [64, 64]
    float* out = (float*)d_out;

    const int N = in_sizes[0] / 128;            // 50000
    const int E = in_sizes[1] / 2;              // 800000
    const int* src = ei;
    const int* dst = ei + E;

    const size_t N64 = (size_t)N * 64;
    float* tmp    = (float*)d_ws;               // [N,64]  y = in @ Wl
    float* h      = tmp + N64;                  // [N,64]  layer-1 output
    float* z      = h + N64;                    // [N,64]  layer-2 output
    int*   deg    = (int*)(z + N64);            // [N]
    int*   offs   = deg + N;                    // [N]
    int*   cursor = offs + N;                   // [N]
    int*   csr    = cursor + N;                 // [E]
    int*   bsum   = csr + E;                    // [ceil(N/256)]

    const int nb          = (N + THREADS - 1) / THREADS;       // scan blocks
    const int edge_blocks = (E + THREADS - 1) / THREADS;
    const int gemm_blocks = 2048;
    const int aggr_blocks = (N + 3) / 4;                       // 4 nodes/block
    const int scor_blocks = (E * 16 + THREADS - 1) / THREADS;

    // ---- CSR build (once; shared by both layers) ----
    hipMemsetAsync(deg, 0, (size_t)N * sizeof(int), stream);
    hist_kernel<<<edge_blocks, THREADS, 0, stream>>>(dst, deg, E);
    scan_reduce<<<nb, THREADS, 0, stream>>>(deg, bsum, N);
    scan_top<<<1, THREADS, 0, stream>>>(bsum, nb);
    scan_apply<<<nb, THREADS, 0, stream>>>(deg, bsum, offs, cursor, N);
    place_kernel<<<edge_blocks, THREADS, 0, stream>>>(src, dst, cursor, csr, E);

    // ---- layer 1 ----
    gemm_dual<128><<<gemm_blocks, THREADS, 0, stream>>>(x, W1l, W1r, tmp, h, N);
    aggregate_fused<<<aggr_blocks, THREADS, 0, stream>>>(tmp, csr, offs, deg, h, b1, h, N, 1);

    // ---- layer 2 ----
    gemm_dual<64><<<gemm_blocks, THREADS, 0, stream>>>(h, W2l, W2r, tmp, z, N);
    aggregate_fused<<<aggr_blocks, THREADS, 0, stream>>>(tmp, csr, offs, deg, z, b2, z, N, 0);

    // ---- decode ----
    score_kernel<<<scor_blocks, THREADS, 0, stream>>>(z, src, dst, out, E);
}

// Round 3
// 286.090 us; speedup vs baseline: 5.5564x; 1.1626x over previous
//
#include <hip/hip_runtime.h>
#include <hip/hip_bf16.h>

#define THREADS 256

// ---------------------------------------------------------------------------
// Dual GEMM: outl = in @ Wl, outr = in @ Wr.   in: [nrows, K], W: [K, 64].
// R rows per wave (lane = output column). W staged in LDS [k][64] (2-way
// bank aliasing = free). Row indices wave-uniform => x loads are scalar
// s_load_dwordx4. 8 LDS reads per 64 FMAs => VALU-bound.
// ---------------------------------------------------------------------------
template<int K, int R>
__global__ __launch_bounds__(THREADS) void gemm_dual(
    const float* __restrict__ in, const float* __restrict__ Wl,
    const float* __restrict__ Wr, float* __restrict__ outl,
    float* __restrict__ outr, int nrows)
{
    __shared__ float sWl[K * 64];
    __shared__ float sWr[K * 64];
    for (int i = threadIdx.x; i < K * 64; i += THREADS) {
        sWl[i] = Wl[i];
        sWr[i] = Wr[i];
    }
    __syncthreads();

    const int lane = threadIdx.x & 63;
    const int wid  = threadIdx.x >> 6;
    const int RPB  = 4 * R;                       // rows per block

    for (int base = blockIdx.x * RPB; base < nrows; base += gridDim.x * RPB) {
        const int row0 = __builtin_amdgcn_readfirstlane(base + wid * R);
        if (row0 >= nrows) continue;

        // clamp rows for loads (uniform), guard stores
        int rr[R];
        #pragma unroll
        for (int r = 0; r < R; ++r)
            rr[r] = (row0 + r < nrows) ? (row0 + r) : (nrows - 1);

        float accl[R], accr[R];
        #pragma unroll
        for (int r = 0; r < R; ++r) { accl[r] = 0.f; accr[r] = 0.f; }

        #pragma unroll 2
        for (int k4 = 0; k4 < K / 4; ++k4) {
            const int kb = k4 * 4;
            const float wl0 = sWl[(kb + 0) * 64 + lane];
            const float wl1 = sWl[(kb + 1) * 64 + lane];
            const float wl2 = sWl[(kb + 2) * 64 + lane];
            const float wl3 = sWl[(kb + 3) * 64 + lane];
            const float wr0 = sWr[(kb + 0) * 64 + lane];
            const float wr1 = sWr[(kb + 1) * 64 + lane];
            const float wr2 = sWr[(kb + 2) * 64 + lane];
            const float wr3 = sWr[(kb + 3) * 64 + lane];
            #pragma unroll
            for (int r = 0; r < R; ++r) {
                const float4 xv = *reinterpret_cast<const float4*>(
                    in + (size_t)rr[r] * K + kb);
                accl[r] = fmaf(xv.x, wl0, accl[r]);
                accl[r] = fmaf(xv.y, wl1, accl[r]);
                accl[r] = fmaf(xv.z, wl2, accl[r]);
                accl[r] = fmaf(xv.w, wl3, accl[r]);
                accr[r] = fmaf(xv.x, wr0, accr[r]);
                accr[r] = fmaf(xv.y, wr1, accr[r]);
                accr[r] = fmaf(xv.z, wr2, accr[r]);
                accr[r] = fmaf(xv.w, wr3, accr[r]);
            }
        }

        #pragma unroll
        for (int r = 0; r < R; ++r) {
            if (row0 + r < nrows) {
                outl[(size_t)(row0 + r) * 64 + lane] = accl[r];
                outr[(size_t)(row0 + r) * 64 + lane] = accr[r];
            }
        }
    }
}

// ---------------------------------------------------------------------------
// CSR build: histogram of dst, exclusive scan, placement.
// ---------------------------------------------------------------------------
__global__ __launch_bounds__(THREADS) void hist_kernel(
    const int* __restrict__ dst, int* __restrict__ deg, int nedges)
{
    const int e = blockIdx.x * THREADS + threadIdx.x;
    if (e < nedges) atomicAdd(&deg[dst[e]], 1);
}

__global__ __launch_bounds__(THREADS) void scan_reduce(
    const int* __restrict__ deg, int* __restrict__ bsum, int n)
{
    __shared__ int s[THREADS];
    const int i = blockIdx.x * THREADS + threadIdx.x;
    s[threadIdx.x] = (i < n) ? deg[i] : 0;
    __syncthreads();
    for (int off = THREADS / 2; off > 0; off >>= 1) {
        if (threadIdx.x < off) s[threadIdx.x] += s[threadIdx.x + off];
        __syncthreads();
    }
    if (threadIdx.x == 0) bsum[blockIdx.x] = s[0];
}

// single block; nb <= THREADS
__global__ __launch_bounds__(THREADS) void scan_top(int* __restrict__ bsum, int nb)
{
    __shared__ int s[THREADS];
    const int t = threadIdx.x;
    const int v = (t < nb) ? bsum[t] : 0;
    s[t] = v;
    __syncthreads();
    for (int off = 1; off < THREADS; off <<= 1) {
        const int a = (t >= off) ? s[t - off] : 0;
        __syncthreads();
        s[t] += a;
        __syncthreads();
    }
    if (t < nb) bsum[t] = s[t] - v;   // exclusive
}

__global__ __launch_bounds__(THREADS) void scan_apply(
    const int* __restrict__ deg, const int* __restrict__ bsum,
    int* __restrict__ offs, int* __restrict__ cursor, int n)
{
    __shared__ int s[THREADS];
    const int t = threadIdx.x;
    const int i = blockIdx.x * THREADS + t;
    const int v = (i < n) ? deg[i] : 0;
    s[t] = v;
    __syncthreads();
    for (int off = 1; off < THREADS; off <<= 1) {
        const int a = (t >= off) ? s[t - off] : 0;
        __syncthreads();
        s[t] += a;
        __syncthreads();
    }
    if (i < n) {
        const int ex = bsum[blockIdx.x] + s[t] - v;
        offs[i] = ex;
        cursor[i] = ex;
    }
}

__global__ __launch_bounds__(THREADS) void place_kernel(
    const int* __restrict__ src, const int* __restrict__ dst,
    int* __restrict__ cursor, int* __restrict__ csr, int nedges)
{
    const int e = blockIdx.x * THREADS + threadIdx.x;
    if (e < nedges) {
        const int pos = atomicAdd(&cursor[dst[e]], 1);
        csr[pos] = src[e];
    }
}

// ---------------------------------------------------------------------------
// Fused mean-aggregate + combine:
//   out[node,lane] = [relu]( (sum_{s in csr[node]} y[s,lane]) / max(deg,1)
//                            + bias[lane] + right[node,lane] )
// One wave per node, lane = channel. Edge rows are coalesced 256B gathers.
// ---------------------------------------------------------------------------
__global__ __launch_bounds__(THREADS) void aggregate_fused(
    const float* __restrict__ y, const int* __restrict__ csr,
    const int* __restrict__ offs, const int* __restrict__ deg,
    const float* __restrict__ right, const float* __restrict__ bias,
    float* __restrict__ out, int n, int relu)
{
    int node = blockIdx.x * (THREADS / 64) + (threadIdx.x >> 6);
    if (node >= n) return;
    node = __builtin_amdgcn_readfirstlane(node);   // wave-uniform
    const int lane = threadIdx.x & 63;
    const int start = __builtin_amdgcn_readfirstlane(offs[node]);
    const int d     = __builtin_amdgcn_readfirstlane(deg[node]);

    float acc = 0.f;
    int i = 0;
    for (; i + 4 <= d; i += 4) {
        const int s0 = __builtin_amdgcn_readfirstlane(csr[start + i + 0]);
        const int s1 = __builtin_amdgcn_readfirstlane(csr[start + i + 1]);
        const int s2 = __builtin_amdgcn_readfirstlane(csr[start + i + 2]);
        const int s3 = __builtin_amdgcn_readfirstlane(csr[start + i + 3]);
        const float a0 = y[(size_t)s0 * 64 + lane];
        const float a1 = y[(size_t)s1 * 64 + lane];
        const float a2 = y[(size_t)s2 * 64 + lane];
        const float a3 = y[(size_t)s3 * 64 + lane];
        acc += a0 + a1 + a2 + a3;
    }
    for (; i < d; ++i) {
        const int s = __builtin_amdgcn_readfirstlane(csr[start + i]);
        acc += y[(size_t)s * 64 + lane];
    }

    const float inv = 1.0f / (float)(d > 0 ? d : 1);
    float v = fmaf(acc, inv, bias[lane] + right[(size_t)node * 64 + lane]);
    if (relu) v = fmaxf(v, 0.f);
    out[(size_t)node * 64 + lane] = v;
}

// ---------------------------------------------------------------------------
// out[e] = dot(z[src[e]], z[dst[e]])  over 64 ch; 16 lanes/edge + shfl reduce.
// ---------------------------------------------------------------------------
__global__ __launch_bounds__(THREADS) void score_kernel(
    const float* __restrict__ z, const int* __restrict__ src,
    const int* __restrict__ dst, float* __restrict__ out, int nedges)
{
    const int gid = blockIdx.x * THREADS + threadIdx.x;
    const int e = gid >> 4;
    const int g = gid & 15;
    if (e >= nedges) return;
    const int s = src[e];
    const int d = dst[e];
    const float4 a = *reinterpret_cast<const float4*>(z + (size_t)s * 64 + g * 4);
    const float4 b = *reinterpret_cast<const float4*>(z + (size_t)d * 64 + g * 4);
    float p = a.x * b.x + a.y * b.y + a.z * b.z + a.w * b.w;
    p += __shfl_down(p, 8, 16);
    p += __shfl_down(p, 4, 16);
    p += __shfl_down(p, 2, 16);
    p += __shfl_down(p, 1, 16);
    if (g == 0) out[e] = p;
}

extern "C" void kernel_launch(void* const* d_in, const int* in_sizes, int n_in,
                              void* d_out, int out_size, void* d_ws, size_t ws_size,
                              hipStream_t stream)
{
    const float* x   = (const float*)d_in[0];   // [N, 128]
    const int*   ei  = (const int*)  d_in[1];   // [2, E]
    const float* W1l = (const float*)d_in[2];   // [128, 64]
    const float* b1  = (const float*)d_in[3];   // [64]
    const float* W1r = (const float*)d_in[4];   // [128, 64]
    const float* W2l = (const float*)d_in[5];   // [64, 64]
    const float* b2  = (const float*)d_in[6];   // [64]
    const float* W2r = (const float*)d_in[7];   // [64, 64]
    float* out = (float*)d_out;

    const int N = in_sizes[0] / 128;            // 50000
    const int E = in_sizes[1] / 2;              // 800000
    const int* src = ei;
    const int* dst = ei + E;

    const size_t N64 = (size_t)N * 64;
    float* tmp    = (float*)d_ws;               // [N,64]  y = in @ Wl
    float* h      = tmp + N64;                  // [N,64]  layer-1 output
    float* z      = h + N64;                    // [N,64]  layer-2 output
    int*   deg    = (int*)(z + N64);            // [N]
    int*   offs   = deg + N;                    // [N]
    int*   cursor = offs + N;                   // [N]
    int*   csr    = cursor + N;                 // [E]
    int*   bsum   = csr + E;                    // [ceil(N/256)]

    constexpr int R = 8;                        // rows per wave
    const int nb          = (N + THREADS - 1) / THREADS;       // scan blocks
    const int edge_blocks = (E + THREADS - 1) / THREADS;
    const int gemm_blocks = (N + 4 * R - 1) / (4 * R);
    const int aggr_blocks = (N + 3) / 4;                       // 4 nodes/block
    const int scor_blocks = (E * 16 + THREADS - 1) / THREADS;

    // ---- CSR build (once; shared by both layers) ----
    hipMemsetAsync(deg, 0, (size_t)N * sizeof(int), stream);
    hist_kernel<<<edge_blocks, THREADS, 0, stream>>>(dst, deg, E);
    scan_reduce<<<nb, THREADS, 0, stream>>>(deg, bsum, N);
    scan_top<<<1, THREADS, 0, stream>>>(bsum, nb);
    scan_apply<<<nb, THREADS, 0, stream>>>(deg, bsum, offs, cursor, N);
    place_kernel<<<edge_blocks, THREADS, 0, stream>>>(src, dst, cursor, csr, E);

    // ---- layer 1 ----
    gemm_dual<128, R><<<gemm_blocks, THREADS, 0, stream>>>(x, W1l, W1r, tmp, h, N);
    aggregate_fused<<<aggr_blocks, THREADS, 0, stream>>>(tmp, csr, offs, deg, h, b1, h, N, 1);

    // ---- layer 2 ----
    gemm_dual<64, R><<<gemm_blocks, THREADS, 0, stream>>>(h, W2l, W2r, tmp, z, N);
    aggregate_fused<<<aggr_blocks, THREADS, 0, stream>>>(tmp, csr, offs, deg, z, b2, z, N, 0);

    // ---- decode ----
    score_kernel<<<scor_blocks, THREADS, 0, stream>>>(z, src, dst, out, E);
}